// Round 10
// baseline (359.477 us; speedup 1.0000x reference)
//
#include <hip/hip_runtime.h>
#include <hip/hip_bf16.h>

#define BB 2
#define SS 2048
#define EE 1024
#define HH 16
#define HD 64

typedef __attribute__((ext_vector_type(8))) __bf16 bf16x8;
typedef __attribute__((ext_vector_type(4))) __bf16 bf16x4;
typedef __attribute__((ext_vector_type(4))) float f32x4;

__device__ __forceinline__ void split2(float x, __bf16& h, __bf16& l) {
    h = (__bf16)x;                 // RTNE
    l = (__bf16)(x - (float)h);    // residual
}

// lgkmcnt-only barrier: orders LDS ops block-wide WITHOUT draining the
// outstanding global (nt) stores the way __syncthreads' vmcnt(0) does.
__device__ __forceinline__ void lds_barrier() {
    asm volatile("s_waitcnt lgkmcnt(0)" ::: "memory");
    __builtin_amdgcn_s_barrier();
    __builtin_amdgcn_sched_barrier(0);
}

// ---------------- K1: QKV projection, fused fp32->hi/lo split staging -----
__global__ __launch_bounds__(256) void k_qkv(
    const float* __restrict__ xx, const float* __restrict__ ww,
    const float* __restrict__ bqkv, const float* __restrict__ rel,
    __bf16* __restrict__ qhi_ws, __bf16* __restrict__ qlo_ws,
    __bf16* __restrict__ khi_ws, __bf16* __restrict__ klo_ws,
    __bf16* __restrict__ vt_ws)
{
    __shared__ __bf16 Ahi[128][72], Alo[128][72];
    __shared__ __bf16 Bhi[64][72],  Blo[64][72];

    const int tid = threadIdx.x;
    const int lane = tid & 63;
    const int wv = tid >> 6;
    const int m0 = blockIdx.y * 128;
    const int f0 = blockIdx.x * 64;
    const int wr = (wv >> 1) * 64, wc = (wv & 1) * 32;
    const int lr = lane & 15, lg = lane >> 4;

    f32x4 acc[4][2];
#pragma unroll
    for (int a = 0; a < 4; ++a)
#pragma unroll
        for (int b = 0; b < 2; ++b) acc[a][b] = (f32x4){0.f, 0.f, 0.f, 0.f};

    for (int kt = 0; kt < 16; ++kt) {
        const int k0 = kt * 64;
        __syncthreads();
        {   // stage A tile 128x64: fp32 load -> split -> hi/lo LDS
            const int c = tid & 7, r0 = tid >> 3;
#pragma unroll
            for (int i = 0; i < 4; ++i) {
                const int row = r0 + i * 32;
                const float* gp = xx + (size_t)(m0 + row) * EE + k0 + c * 8;
                const float4 v0 = *(const float4*)gp;
                const float4 v1 = *(const float4*)(gp + 4);
                float t[8] = {v0.x, v0.y, v0.z, v0.w, v1.x, v1.y, v1.z, v1.w};
                bf16x8 hi, lo;
#pragma unroll
                for (int e = 0; e < 8; ++e) {
                    __bf16 h, l; split2(t[e], h, l);
                    hi[e] = h; lo[e] = l;
                }
                *(bf16x8*)&Ahi[row][c * 8] = hi;
                *(bf16x8*)&Alo[row][c * 8] = lo;
            }
        }
        {   // stage B tile 64x64: fp32 load -> split -> hi/lo LDS
            const int c = tid & 7, r0 = tid >> 3;
#pragma unroll
            for (int i = 0; i < 2; ++i) {
                const int row = r0 + i * 32;
                const float* gp = ww + (size_t)(f0 + row) * EE + k0 + c * 8;
                const float4 v0 = *(const float4*)gp;
                const float4 v1 = *(const float4*)(gp + 4);
                float t[8] = {v0.x, v0.y, v0.z, v0.w, v1.x, v1.y, v1.z, v1.w};
                bf16x8 hi, lo;
#pragma unroll
                for (int e = 0; e < 8; ++e) {
                    __bf16 h, l; split2(t[e], h, l);
                    hi[e] = h; lo[e] = l;
                }
                *(bf16x8*)&Bhi[row][c * 8] = hi;
                *(bf16x8*)&Blo[row][c * 8] = lo;
            }
        }
        __syncthreads();
#pragma unroll
        for (int ks = 0; ks < 2; ++ks) {
            const int koff = ks * 32 + lg * 8;
            bf16x8 ah[4], al[4], bh[2], bl[2];
#pragma unroll
            for (int rt = 0; rt < 4; ++rt) {
                ah[rt] = *(const bf16x8*)&Ahi[wr + rt * 16 + lr][koff];
                al[rt] = *(const bf16x8*)&Alo[wr + rt * 16 + lr][koff];
            }
#pragma unroll
            for (int ct = 0; ct < 2; ++ct) {
                bh[ct] = *(const bf16x8*)&Bhi[wc + ct * 16 + lr][koff];
                bl[ct] = *(const bf16x8*)&Blo[wc + ct * 16 + lr][koff];
            }
#pragma unroll
            for (int rt = 0; rt < 4; ++rt)
#pragma unroll
                for (int ct = 0; ct < 2; ++ct) {
                    acc[rt][ct] = __builtin_amdgcn_mfma_f32_16x16x32_bf16(ah[rt], bh[ct], acc[rt][ct], 0, 0, 0);
                    acc[rt][ct] = __builtin_amdgcn_mfma_f32_16x16x32_bf16(al[rt], bh[ct], acc[rt][ct], 0, 0, 0);
                    acc[rt][ct] = __builtin_amdgcn_mfma_f32_16x16x32_bf16(ah[rt], bl[ct], acc[rt][ct], 0, 0, 0);
                }
        }
    }

    const int blk = f0 >> 6;             // 0..47
    const int h = blk / 3, typ = blk % 3;
#pragma unroll
    for (int rt = 0; rt < 4; ++rt) {
        const int m = m0 + wr + rt * 16 + lg * 4;
        const int b = m >> 11, s = m & 2047;
#pragma unroll
        for (int ct = 0; ct < 2; ++ct) {
            const int d = wc + ct * 16 + lr;
            const float bq = bqkv[f0 + d];
            if (typ == 0) {
                const size_t base = ((size_t)(b * HH + h) * SS + s) * HD + d;
#pragma unroll
                for (int r = 0; r < 4; ++r) {
                    __bf16 hh, ll; split2(acc[rt][ct][r] + bq, hh, ll);
                    qhi_ws[base + (size_t)r * HD] = hh;
                    qlo_ws[base + (size_t)r * HD] = ll;
                }
            } else if (typ == 1) {
                const size_t base = ((size_t)(b * HH + h) * SS + s) * HD + d;
                const size_t rb = ((size_t)h * SS + s) * HD + d;
#pragma unroll
                for (int r = 0; r < 4; ++r) {
                    const float t = (acc[rt][ct][r] + bq) * 0.125f + rel[rb + (size_t)r * HD];
                    __bf16 hh, ll; split2(t, hh, ll);
                    khi_ws[base + (size_t)r * HD] = hh;
                    klo_ws[base + (size_t)r * HD] = ll;
                }
            } else {
                const size_t base = ((size_t)(b * HH + h) * HD + d) * SS + s;
                bf16x4 pk;
#pragma unroll
                for (int r = 0; r < 4; ++r) pk[r] = (__bf16)(acc[rt][ct][r] + bq);
                *(bf16x4*)&vt_ws[base] = pk;
            }
        }
    }
}

// ---------------- K2: two-pass attention, streaming nt stores -------------
// As round 9 (block-shared dbuf K/V staging, 8 waves x 32 q-rows, one
// bh/block) plus: (1) per-jt barrier is lgkmcnt-only (raw s_barrier), so
// the weights nt stores stay in flight ACROSS j-tiles instead of draining
// at every __syncthreads; (2) weights stored fp32 directly from the QK
// accumulators (no bf16 round-trip through LDS; stores issue early and
// spread through the tile). P->LDS (bf16) kept only for the PV transpose.
__global__ __launch_bounds__(512, 1) void k_attn9(
    const __bf16* __restrict__ qhi_ws, const __bf16* __restrict__ qlo_ws,
    const __bf16* __restrict__ khi_ws, const __bf16* __restrict__ klo_ws,
    const __bf16* __restrict__ vt_ws,
    float* __restrict__ wts, __bf16* __restrict__ av_ws)
{
    __shared__ __bf16 KH[2][64][72], KL[2][64][72], VTS[2][64][72]; // 55.3 KB
    __shared__ __bf16 P[8][32][72];                                 // 36.9 KB

    const int tid = threadIdx.x;
    const int lane = tid & 63;
    const int wv = tid >> 6;          // 0..7
    const int lr = lane & 15, lg = lane >> 4;

    // XCD swizzle: 256 blocks; XCD k gets wgid k*32..k*32+31 = 4 whole bh
    const int wgid = (blockIdx.x & 7) * 32 + (blockIdx.x >> 3);
    const int bh = wgid >> 3;
    const int q0 = (wgid & 7) * 256 + wv * 32;
    const size_t kvb = (size_t)bh * SS * HD;

    const int srow = tid >> 3;          // 0..63
    const int scol = (tid & 7) * 8;     // 0..56

    // q fragments (hi/lo), 2 row-groups x 2 k-chunks
    bf16x8 qh[2][2], ql[2][2];
#pragma unroll
    for (int rg = 0; rg < 2; ++rg) {
        const size_t ro = kvb + (size_t)(q0 + rg * 16 + lr) * HD + lg * 8;
#pragma unroll
        for (int kk = 0; kk < 2; ++kk) {
            qh[rg][kk] = *(const bf16x8*)(qhi_ws + ro + kk * 32);
            ql[rg][kk] = *(const bf16x8*)(qlo_ws + ro + kk * 32);
        }
    }

    const __bf16* khp = khi_ws + kvb;
    const __bf16* klp = klo_ws + kvb;
    const __bf16* vtp = vt_ws + kvb;

    // ---- pass 1: Z ----
    float z[2][4] = {{0.f,0.f,0.f,0.f},{0.f,0.f,0.f,0.f}};
    {
        bf16x8 sh = *(const bf16x8*)(khp + (size_t)srow * HD + scol);
        bf16x8 sl = *(const bf16x8*)(klp + (size_t)srow * HD + scol);
        *(bf16x8*)&KH[0][srow][scol] = sh;
        *(bf16x8*)&KL[0][srow][scol] = sl;
        lds_barrier();
        for (int jt = 0; jt < 32; ++jt) {
            const int cur = jt & 1;
            if (jt + 1 < 32) {               // prefetch next tile into regs
                const size_t ro = ((size_t)(jt + 1) * 64 + srow) * HD + scol;
                sh = *(const bf16x8*)(khp + ro);
                sl = *(const bf16x8*)(klp + ro);
            }
#pragma unroll
            for (int cg = 0; cg < 4; ++cg) {
                const bf16x8 kh0 = *(const bf16x8*)&KH[cur][cg * 16 + lr][lg * 8];
                const bf16x8 kh1 = *(const bf16x8*)&KH[cur][cg * 16 + lr][32 + lg * 8];
                const bf16x8 kl0 = *(const bf16x8*)&KL[cur][cg * 16 + lr][lg * 8];
                const bf16x8 kl1 = *(const bf16x8*)&KL[cur][cg * 16 + lr][32 + lg * 8];
#pragma unroll
                for (int rg = 0; rg < 2; ++rg) {
                    f32x4 u = (f32x4){0.f, 0.f, 0.f, 0.f};
                    u = __builtin_amdgcn_mfma_f32_16x16x32_bf16(qh[rg][0], kh0, u, 0, 0, 0);
                    u = __builtin_amdgcn_mfma_f32_16x16x32_bf16(qh[rg][1], kh1, u, 0, 0, 0);
                    u = __builtin_amdgcn_mfma_f32_16x16x32_bf16(ql[rg][0], kh0, u, 0, 0, 0);
                    u = __builtin_amdgcn_mfma_f32_16x16x32_bf16(ql[rg][1], kh1, u, 0, 0, 0);
                    u = __builtin_amdgcn_mfma_f32_16x16x32_bf16(qh[rg][0], kl0, u, 0, 0, 0);
                    u = __builtin_amdgcn_mfma_f32_16x16x32_bf16(qh[rg][1], kl1, u, 0, 0, 0);
#pragma unroll
                    for (int r = 0; r < 4; ++r) z[rg][r] += __expf(u[r]);
                }
            }
            if (jt + 1 < 32) {               // stage next tile (regs -> LDS)
                *(bf16x8*)&KH[cur ^ 1][srow][scol] = sh;
                *(bf16x8*)&KL[cur ^ 1][srow][scol] = sl;
            }
            lds_barrier();
        }
    }
    // butterfly over the 16 lr lanes -> every lane holds Z for its rows
#pragma unroll
    for (int m = 1; m < 16; m <<= 1)
#pragma unroll
        for (int rg = 0; rg < 2; ++rg)
#pragma unroll
            for (int r = 0; r < 4; ++r) z[rg][r] += __shfl_xor(z[rg][r], m, 64);
    float rz[2][4];
#pragma unroll
    for (int rg = 0; rg < 2; ++rg)
#pragma unroll
        for (int r = 0; r < 4; ++r) rz[rg][r] = 1.0f / z[rg][r];

    // ---- pass 2: weights + PV ----
    f32x4 pv[2][4];
#pragma unroll
    for (int rg = 0; rg < 2; ++rg)
#pragma unroll
        for (int dg = 0; dg < 4; ++dg) pv[rg][dg] = (f32x4){0.f, 0.f, 0.f, 0.f};

    float* wbase = wts + ((size_t)bh * SS + q0) * SS;

    {
        bf16x8 sh = *(const bf16x8*)(khp + (size_t)srow * HD + scol);
        bf16x8 sl = *(const bf16x8*)(klp + (size_t)srow * HD + scol);
        bf16x8 sv = *(const bf16x8*)(vtp + (size_t)srow * SS + scol);
        *(bf16x8*)&KH[0][srow][scol] = sh;
        *(bf16x8*)&KL[0][srow][scol] = sl;
        *(bf16x8*)&VTS[0][srow][scol] = sv;
        lds_barrier();
        for (int jt = 0; jt < 32; ++jt) {
            const int cur = jt & 1;
            const int j0 = jt * 64;
            if (jt + 1 < 32) {
                const size_t ro = ((size_t)(jt + 1) * 64 + srow) * HD + scol;
                sh = *(const bf16x8*)(khp + ro);
                sl = *(const bf16x8*)(klp + ro);
                sv = *(const bf16x8*)(vtp + (size_t)srow * SS + j0 + 64 + scol);
            }
            // QK + exp; weights stored fp32 straight from accumulators (nt,
            // stays in flight past the lgkmcnt-only barrier); P (bf16) to
            // wave-private LDS strip for the PV transpose.
#pragma unroll
            for (int cg = 0; cg < 4; ++cg) {
                const bf16x8 kh0 = *(const bf16x8*)&KH[cur][cg * 16 + lr][lg * 8];
                const bf16x8 kh1 = *(const bf16x8*)&KH[cur][cg * 16 + lr][32 + lg * 8];
                const bf16x8 kl0 = *(const bf16x8*)&KL[cur][cg * 16 + lr][lg * 8];
                const bf16x8 kl1 = *(const bf16x8*)&KL[cur][cg * 16 + lr][32 + lg * 8];
#pragma unroll
                for (int rg = 0; rg < 2; ++rg) {
                    f32x4 u = (f32x4){0.f, 0.f, 0.f, 0.f};
                    u = __builtin_amdgcn_mfma_f32_16x16x32_bf16(qh[rg][0], kh0, u, 0, 0, 0);
                    u = __builtin_amdgcn_mfma_f32_16x16x32_bf16(qh[rg][1], kh1, u, 0, 0, 0);
                    u = __builtin_amdgcn_mfma_f32_16x16x32_bf16(ql[rg][0], kh0, u, 0, 0, 0);
                    u = __builtin_amdgcn_mfma_f32_16x16x32_bf16(ql[rg][1], kh1, u, 0, 0, 0);
                    u = __builtin_amdgcn_mfma_f32_16x16x32_bf16(qh[rg][0], kl0, u, 0, 0, 0);
                    u = __builtin_amdgcn_mfma_f32_16x16x32_bf16(qh[rg][1], kl1, u, 0, 0, 0);
#pragma unroll
                    for (int r = 0; r < 4; ++r) {
                        const float w = __expf(u[r]) * rz[rg][r];
                        const int row = rg * 16 + lg * 4 + r;
                        __builtin_nontemporal_store(
                            w, wbase + (size_t)row * SS + j0 + cg * 16 + lr);
                        P[wv][row][cg * 16 + lr] = (__bf16)w;
                    }
                }
            }
            // PV from staged V + P strip
            {
                bf16x8 vb[4][2];
#pragma unroll
                for (int dg = 0; dg < 4; ++dg)
#pragma unroll
                    for (int kk = 0; kk < 2; ++kk)
                        vb[dg][kk] = *(const bf16x8*)&VTS[cur][dg * 16 + lr][kk * 32 + lg * 8];
#pragma unroll
                for (int rg = 0; rg < 2; ++rg) {
                    const bf16x8 pa0 = *(const bf16x8*)&P[wv][rg * 16 + lr][lg * 8];
                    const bf16x8 pa1 = *(const bf16x8*)&P[wv][rg * 16 + lr][32 + lg * 8];
#pragma unroll
                    for (int dg = 0; dg < 4; ++dg) {
                        pv[rg][dg] = __builtin_amdgcn_mfma_f32_16x16x32_bf16(pa0, vb[dg][0], pv[rg][dg], 0, 0, 0);
                        pv[rg][dg] = __builtin_amdgcn_mfma_f32_16x16x32_bf16(pa1, vb[dg][1], pv[rg][dg], 0, 0, 0);
                    }
                }
            }
            // stage next tile (regs -> LDS), then lgkmcnt-only barrier
            if (jt + 1 < 32) {
                *(bf16x8*)&KH[cur ^ 1][srow][scol] = sh;
                *(bf16x8*)&KL[cur ^ 1][srow][scol] = sl;
                *(bf16x8*)&VTS[cur ^ 1][srow][scol] = sv;
            }
            lds_barrier();
        }
    }

    {   // av -> bf16 ws [B][S][E]
        const int b = bh >> 4, h = bh & 15;
#pragma unroll
        for (int rg = 0; rg < 2; ++rg)
#pragma unroll
            for (int dg = 0; dg < 4; ++dg)
#pragma unroll
                for (int r = 0; r < 4; ++r) {
                    const int s = q0 + rg * 16 + lg * 4 + r;
                    av_ws[((size_t)(b * SS + s)) * EE + h * HD + dg * 16 + lr] =
                        (__bf16)pv[rg][dg][r];
                }
    }
}

// ---------------- K3: out projection (plain bf16) -------------------------
__global__ __launch_bounds__(256) void k_oproj(
    const __bf16* __restrict__ av_ws, const float* __restrict__ w_out,
    const float* __restrict__ b_out, float* __restrict__ out)
{
    __shared__ __bf16 Abf[128][72];
    __shared__ __bf16 Bbf[64][72];
    const int tid = threadIdx.x;
    const int lane = tid & 63;
    const int wv = tid >> 6;
    const int m0 = blockIdx.y * 128, f0 = blockIdx.x * 64;
    const int wr = (wv >> 1) * 64, wc = (wv & 1) * 32;
    const int lr = lane & 15, lg = lane >> 4;

    f32x4 acc[4][2];
#pragma unroll
    for (int a = 0; a < 4; ++a)
#pragma unroll
        for (int b = 0; b < 2; ++b) acc[a][b] = (f32x4){0.f, 0.f, 0.f, 0.f};

    for (int kt = 0; kt < 16; ++kt) {
        const int k0 = kt * 64;
        __syncthreads();
        {
            const int c = tid & 7, r0 = tid >> 3;
#pragma unroll
            for (int i = 0; i < 4; ++i) {
                const int row = r0 + i * 32;
                *(bf16x8*)&Abf[row][c * 8] =
                    *(const bf16x8*)(av_ws + (size_t)(m0 + row) * EE + k0 + c * 8);
            }
        }
        {
            const int c = tid & 15, r0 = tid >> 4;
#pragma unroll
            for (int i = 0; i < 4; ++i) {
                const int row = r0 + i * 16;
                const float4 v = *(const float4*)(w_out + (size_t)(f0 + row) * EE + k0 + c * 4);
                bf16x4 pk;
                pk[0] = (__bf16)v.x; pk[1] = (__bf16)v.y;
                pk[2] = (__bf16)v.z; pk[3] = (__bf16)v.w;
                *(bf16x4*)&Bbf[row][c * 4] = pk;
            }
        }
        __syncthreads();
#pragma unroll
        for (int ks = 0; ks < 2; ++ks) {
            const int koff = ks * 32 + lg * 8;
            bf16x8 a[4], b[2];
#pragma unroll
            for (int rt = 0; rt < 4; ++rt) a[rt] = *(const bf16x8*)&Abf[wr + rt * 16 + lr][koff];
#pragma unroll
            for (int ct = 0; ct < 2; ++ct) b[ct] = *(const bf16x8*)&Bbf[wc + ct * 16 + lr][koff];
#pragma unroll
            for (int rt = 0; rt < 4; ++rt)
#pragma unroll
                for (int ct = 0; ct < 2; ++ct)
                    acc[rt][ct] = __builtin_amdgcn_mfma_f32_16x16x32_bf16(a[rt], b[ct], acc[rt][ct], 0, 0, 0);
        }
    }
#pragma unroll
    for (int rt = 0; rt < 4; ++rt) {
        const int m = m0 + wr + rt * 16 + lg * 4;
#pragma unroll
        for (int ct = 0; ct < 2; ++ct) {
            const int f = f0 + wc + ct * 16 + lr;
            const float bo = b_out[f];
#pragma unroll
            for (int r = 0; r < 4; ++r)
                __builtin_nontemporal_store(acc[rt][ct][r] + bo,
                                            out + (size_t)(m + r) * EE + f);
        }
    }
}

extern "C" void kernel_launch(void* const* d_in, const int* in_sizes, int n_in,
                              void* d_out, int out_size, void* d_ws, size_t ws_size,
                              hipStream_t stream)
{
    const float* x    = (const float*)d_in[0];
    const float* wqkv = (const float*)d_in[1];
    const float* bqkv = (const float*)d_in[2];
    const float* wo   = (const float*)d_in[3];
    const float* bo   = (const float*)d_in[4];
    const float* rel  = (const float*)d_in[5];

    float* out = (float*)d_out;
    float* wts = out + (size_t)BB * SS * EE;      // weights region, written by K2

    const size_t NQ = (size_t)BB * HH * SS * HD;  // 4M elements
    __bf16* qhi_ws = (__bf16*)d_ws;               // 8 MB each
    __bf16* qlo_ws = qhi_ws + NQ;
    __bf16* khi_ws = qlo_ws + NQ;
    __bf16* klo_ws = khi_ws + NQ;
    __bf16* vt_ws  = klo_ws + NQ;
    __bf16* av_ws  = vt_ws + NQ;                  // ws total: 48 MB

    k_qkv<<<dim3(48, 32), 256, 0, stream>>>(x, wqkv, bqkv, rel,
                                            qhi_ws, qlo_ws, khi_ws, klo_ws, vt_ws);
    k_attn9<<<dim3(256), 512, 0, stream>>>(qhi_ws, qlo_ws, khi_ws, klo_ws,
                                           vt_ws, wts, av_ws);
    k_oproj<<<dim3(EE / 64, (BB * SS) / 128), 256, 0, stream>>>(av_ws, wo, bo, out);
}

// Round 11
// 297.270 us; speedup vs baseline: 1.2093x; 1.2093x over previous
//
#include <hip/hip_runtime.h>
#include <hip/hip_bf16.h>

#define BB 2
#define SS 2048
#define EE 1024
#define HH 16
#define HD 64

typedef __attribute__((ext_vector_type(8))) __bf16 bf16x8;
typedef __attribute__((ext_vector_type(4))) __bf16 bf16x4;
typedef __attribute__((ext_vector_type(4))) float f32x4;

__device__ __forceinline__ void split2(float x, __bf16& h, __bf16& l) {
    h = (__bf16)x;                 // RTNE
    l = (__bf16)(x - (float)h);    // residual
}

// lgkmcnt-only barrier: orders LDS ops block-wide WITHOUT draining the
// outstanding global (nt) stores the way __syncthreads' vmcnt(0) does.
__device__ __forceinline__ void lds_barrier() {
    asm volatile("s_waitcnt lgkmcnt(0)" ::: "memory");
    __builtin_amdgcn_s_barrier();
    __builtin_amdgcn_sched_barrier(0);
}

// ---------------- K1: QKV projection, fused fp32->hi/lo split staging -----
__global__ __launch_bounds__(256) void k_qkv(
    const float* __restrict__ xx, const float* __restrict__ ww,
    const float* __restrict__ bqkv, const float* __restrict__ rel,
    __bf16* __restrict__ qhi_ws, __bf16* __restrict__ qlo_ws,
    __bf16* __restrict__ khi_ws, __bf16* __restrict__ klo_ws,
    __bf16* __restrict__ vt_ws)
{
    __shared__ __bf16 Ahi[128][72], Alo[128][72];
    __shared__ __bf16 Bhi[64][72],  Blo[64][72];

    const int tid = threadIdx.x;
    const int lane = tid & 63;
    const int wv = tid >> 6;
    const int m0 = blockIdx.y * 128;
    const int f0 = blockIdx.x * 64;
    const int wr = (wv >> 1) * 64, wc = (wv & 1) * 32;
    const int lr = lane & 15, lg = lane >> 4;

    f32x4 acc[4][2];
#pragma unroll
    for (int a = 0; a < 4; ++a)
#pragma unroll
        for (int b = 0; b < 2; ++b) acc[a][b] = (f32x4){0.f, 0.f, 0.f, 0.f};

    for (int kt = 0; kt < 16; ++kt) {
        const int k0 = kt * 64;
        __syncthreads();
        {   // stage A tile 128x64: fp32 load -> split -> hi/lo LDS
            const int c = tid & 7, r0 = tid >> 3;
#pragma unroll
            for (int i = 0; i < 4; ++i) {
                const int row = r0 + i * 32;
                const float* gp = xx + (size_t)(m0 + row) * EE + k0 + c * 8;
                const float4 v0 = *(const float4*)gp;
                const float4 v1 = *(const float4*)(gp + 4);
                float t[8] = {v0.x, v0.y, v0.z, v0.w, v1.x, v1.y, v1.z, v1.w};
                bf16x8 hi, lo;
#pragma unroll
                for (int e = 0; e < 8; ++e) {
                    __bf16 h, l; split2(t[e], h, l);
                    hi[e] = h; lo[e] = l;
                }
                *(bf16x8*)&Ahi[row][c * 8] = hi;
                *(bf16x8*)&Alo[row][c * 8] = lo;
            }
        }
        {   // stage B tile 64x64: fp32 load -> split -> hi/lo LDS
            const int c = tid & 7, r0 = tid >> 3;
#pragma unroll
            for (int i = 0; i < 2; ++i) {
                const int row = r0 + i * 32;
                const float* gp = ww + (size_t)(f0 + row) * EE + k0 + c * 8;
                const float4 v0 = *(const float4*)gp;
                const float4 v1 = *(const float4*)(gp + 4);
                float t[8] = {v0.x, v0.y, v0.z, v0.w, v1.x, v1.y, v1.z, v1.w};
                bf16x8 hi, lo;
#pragma unroll
                for (int e = 0; e < 8; ++e) {
                    __bf16 h, l; split2(t[e], h, l);
                    hi[e] = h; lo[e] = l;
                }
                *(bf16x8*)&Bhi[row][c * 8] = hi;
                *(bf16x8*)&Blo[row][c * 8] = lo;
            }
        }
        __syncthreads();
#pragma unroll
        for (int ks = 0; ks < 2; ++ks) {
            const int koff = ks * 32 + lg * 8;
            bf16x8 ah[4], al[4], bh[2], bl[2];
#pragma unroll
            for (int rt = 0; rt < 4; ++rt) {
                ah[rt] = *(const bf16x8*)&Ahi[wr + rt * 16 + lr][koff];
                al[rt] = *(const bf16x8*)&Alo[wr + rt * 16 + lr][koff];
            }
#pragma unroll
            for (int ct = 0; ct < 2; ++ct) {
                bh[ct] = *(const bf16x8*)&Bhi[wc + ct * 16 + lr][koff];
                bl[ct] = *(const bf16x8*)&Blo[wc + ct * 16 + lr][koff];
            }
#pragma unroll
            for (int rt = 0; rt < 4; ++rt)
#pragma unroll
                for (int ct = 0; ct < 2; ++ct) {
                    acc[rt][ct] = __builtin_amdgcn_mfma_f32_16x16x32_bf16(ah[rt], bh[ct], acc[rt][ct], 0, 0, 0);
                    acc[rt][ct] = __builtin_amdgcn_mfma_f32_16x16x32_bf16(al[rt], bh[ct], acc[rt][ct], 0, 0, 0);
                    acc[rt][ct] = __builtin_amdgcn_mfma_f32_16x16x32_bf16(ah[rt], bl[ct], acc[rt][ct], 0, 0, 0);
                }
        }
    }

    const int blk = f0 >> 6;             // 0..47
    const int h = blk / 3, typ = blk % 3;
#pragma unroll
    for (int rt = 0; rt < 4; ++rt) {
        const int m = m0 + wr + rt * 16 + lg * 4;
        const int b = m >> 11, s = m & 2047;
#pragma unroll
        for (int ct = 0; ct < 2; ++ct) {
            const int d = wc + ct * 16 + lr;
            const float bq = bqkv[f0 + d];
            if (typ == 0) {
                const size_t base = ((size_t)(b * HH + h) * SS + s) * HD + d;
#pragma unroll
                for (int r = 0; r < 4; ++r) {
                    __bf16 hh, ll; split2(acc[rt][ct][r] + bq, hh, ll);
                    qhi_ws[base + (size_t)r * HD] = hh;
                    qlo_ws[base + (size_t)r * HD] = ll;
                }
            } else if (typ == 1) {
                const size_t base = ((size_t)(b * HH + h) * SS + s) * HD + d;
                const size_t rb = ((size_t)h * SS + s) * HD + d;
#pragma unroll
                for (int r = 0; r < 4; ++r) {
                    const float t = (acc[rt][ct][r] + bq) * 0.125f + rel[rb + (size_t)r * HD];
                    __bf16 hh, ll; split2(t, hh, ll);
                    khi_ws[base + (size_t)r * HD] = hh;
                    klo_ws[base + (size_t)r * HD] = ll;
                }
            } else {
                const size_t base = ((size_t)(b * HH + h) * HD + d) * SS + s;
                bf16x4 pk;
#pragma unroll
                for (int r = 0; r < 4; ++r) pk[r] = (__bf16)(acc[rt][ct][r] + bq);
                *(bf16x4*)&vt_ws[base] = pk;
            }
        }
    }
}

// ---------------- K2: two-pass attention (round-9 structure) --------------
// Round-9 k_attn8 with EXACTLY ONE change: the per-jt __syncthreads is
// replaced by an lgkmcnt-only barrier, so the float4 nt weights stores
// stay in flight across j-tiles instead of draining at every barrier.
// Store path (P-strip -> 8x float4 nt stores, issued after the 3 prefetch
// loads) is round-9's: compiler can wait vmcnt(8) for staging while the
// stores remain outstanding.
__global__ __launch_bounds__(512, 1) void k_attn10(
    const __bf16* __restrict__ qhi_ws, const __bf16* __restrict__ qlo_ws,
    const __bf16* __restrict__ khi_ws, const __bf16* __restrict__ klo_ws,
    const __bf16* __restrict__ vt_ws,
    float* __restrict__ wts, __bf16* __restrict__ av_ws)
{
    __shared__ __bf16 KH[2][64][72], KL[2][64][72], VTS[2][64][72]; // 55.3 KB
    __shared__ __bf16 P[8][32][72];                                 // 36.9 KB

    const int tid = threadIdx.x;
    const int lane = tid & 63;
    const int wv = tid >> 6;          // 0..7
    const int lr = lane & 15, lg = lane >> 4;

    // XCD swizzle: 256 blocks; XCD k gets wgid k*32..k*32+31 = 4 whole bh
    const int wgid = (blockIdx.x & 7) * 32 + (blockIdx.x >> 3);
    const int bh = wgid >> 3;
    const int q0 = (wgid & 7) * 256 + wv * 32;
    const size_t kvb = (size_t)bh * SS * HD;

    const int srow = tid >> 3;          // 0..63
    const int scol = (tid & 7) * 8;     // 0..56

    // q fragments (hi/lo), 2 row-groups x 2 k-chunks
    bf16x8 qh[2][2], ql[2][2];
#pragma unroll
    for (int rg = 0; rg < 2; ++rg) {
        const size_t ro = kvb + (size_t)(q0 + rg * 16 + lr) * HD + lg * 8;
#pragma unroll
        for (int kk = 0; kk < 2; ++kk) {
            qh[rg][kk] = *(const bf16x8*)(qhi_ws + ro + kk * 32);
            ql[rg][kk] = *(const bf16x8*)(qlo_ws + ro + kk * 32);
        }
    }

    const __bf16* khp = khi_ws + kvb;
    const __bf16* klp = klo_ws + kvb;
    const __bf16* vtp = vt_ws + kvb;

    // ---- pass 1: Z ----
    float z[2][4] = {{0.f,0.f,0.f,0.f},{0.f,0.f,0.f,0.f}};
    {
        bf16x8 sh = *(const bf16x8*)(khp + (size_t)srow * HD + scol);
        bf16x8 sl = *(const bf16x8*)(klp + (size_t)srow * HD + scol);
        *(bf16x8*)&KH[0][srow][scol] = sh;
        *(bf16x8*)&KL[0][srow][scol] = sl;
        lds_barrier();
        for (int jt = 0; jt < 32; ++jt) {
            const int cur = jt & 1;
            if (jt + 1 < 32) {               // prefetch next tile into regs
                const size_t ro = ((size_t)(jt + 1) * 64 + srow) * HD + scol;
                sh = *(const bf16x8*)(khp + ro);
                sl = *(const bf16x8*)(klp + ro);
            }
#pragma unroll
            for (int cg = 0; cg < 4; ++cg) {
                const bf16x8 kh0 = *(const bf16x8*)&KH[cur][cg * 16 + lr][lg * 8];
                const bf16x8 kh1 = *(const bf16x8*)&KH[cur][cg * 16 + lr][32 + lg * 8];
                const bf16x8 kl0 = *(const bf16x8*)&KL[cur][cg * 16 + lr][lg * 8];
                const bf16x8 kl1 = *(const bf16x8*)&KL[cur][cg * 16 + lr][32 + lg * 8];
#pragma unroll
                for (int rg = 0; rg < 2; ++rg) {
                    f32x4 u = (f32x4){0.f, 0.f, 0.f, 0.f};
                    u = __builtin_amdgcn_mfma_f32_16x16x32_bf16(qh[rg][0], kh0, u, 0, 0, 0);
                    u = __builtin_amdgcn_mfma_f32_16x16x32_bf16(qh[rg][1], kh1, u, 0, 0, 0);
                    u = __builtin_amdgcn_mfma_f32_16x16x32_bf16(ql[rg][0], kh0, u, 0, 0, 0);
                    u = __builtin_amdgcn_mfma_f32_16x16x32_bf16(ql[rg][1], kh1, u, 0, 0, 0);
                    u = __builtin_amdgcn_mfma_f32_16x16x32_bf16(qh[rg][0], kl0, u, 0, 0, 0);
                    u = __builtin_amdgcn_mfma_f32_16x16x32_bf16(qh[rg][1], kl1, u, 0, 0, 0);
#pragma unroll
                    for (int r = 0; r < 4; ++r) z[rg][r] += __expf(u[r]);
                }
            }
            if (jt + 1 < 32) {               // stage next tile (regs -> LDS)
                *(bf16x8*)&KH[cur ^ 1][srow][scol] = sh;
                *(bf16x8*)&KL[cur ^ 1][srow][scol] = sl;
            }
            lds_barrier();
        }
    }
    // butterfly over the 16 lr lanes -> every lane holds Z for its rows
#pragma unroll
    for (int m = 1; m < 16; m <<= 1)
#pragma unroll
        for (int rg = 0; rg < 2; ++rg)
#pragma unroll
            for (int r = 0; r < 4; ++r) z[rg][r] += __shfl_xor(z[rg][r], m, 64);
    float rz[2][4];
#pragma unroll
    for (int rg = 0; rg < 2; ++rg)
#pragma unroll
        for (int r = 0; r < 4; ++r) rz[rg][r] = 1.0f / z[rg][r];

    // ---- pass 2: weights + PV ----
    f32x4 pv[2][4];
#pragma unroll
    for (int rg = 0; rg < 2; ++rg)
#pragma unroll
        for (int dg = 0; dg < 4; ++dg) pv[rg][dg] = (f32x4){0.f, 0.f, 0.f, 0.f};

    float* wbase = wts + ((size_t)bh * SS + q0) * SS;

    {
        bf16x8 sh = *(const bf16x8*)(khp + (size_t)srow * HD + scol);
        bf16x8 sl = *(const bf16x8*)(klp + (size_t)srow * HD + scol);
        bf16x8 sv = *(const bf16x8*)(vtp + (size_t)srow * SS + scol);
        *(bf16x8*)&KH[0][srow][scol] = sh;
        *(bf16x8*)&KL[0][srow][scol] = sl;
        *(bf16x8*)&VTS[0][srow][scol] = sv;
        lds_barrier();
        for (int jt = 0; jt < 32; ++jt) {
            const int cur = jt & 1;
            const int j0 = jt * 64;
            if (jt + 1 < 32) {
                const size_t ro = ((size_t)(jt + 1) * 64 + srow) * HD + scol;
                sh = *(const bf16x8*)(khp + ro);
                sl = *(const bf16x8*)(klp + ro);
                sv = *(const bf16x8*)(vtp + (size_t)srow * SS + j0 + 64 + scol);
            }
            // QK + exp -> normalized P (bf16) in wave-private LDS strip
#pragma unroll
            for (int cg = 0; cg < 4; ++cg) {
                const bf16x8 kh0 = *(const bf16x8*)&KH[cur][cg * 16 + lr][lg * 8];
                const bf16x8 kh1 = *(const bf16x8*)&KH[cur][cg * 16 + lr][32 + lg * 8];
                const bf16x8 kl0 = *(const bf16x8*)&KL[cur][cg * 16 + lr][lg * 8];
                const bf16x8 kl1 = *(const bf16x8*)&KL[cur][cg * 16 + lr][32 + lg * 8];
#pragma unroll
                for (int rg = 0; rg < 2; ++rg) {
                    f32x4 u = (f32x4){0.f, 0.f, 0.f, 0.f};
                    u = __builtin_amdgcn_mfma_f32_16x16x32_bf16(qh[rg][0], kh0, u, 0, 0, 0);
                    u = __builtin_amdgcn_mfma_f32_16x16x32_bf16(qh[rg][1], kh1, u, 0, 0, 0);
                    u = __builtin_amdgcn_mfma_f32_16x16x32_bf16(ql[rg][0], kh0, u, 0, 0, 0);
                    u = __builtin_amdgcn_mfma_f32_16x16x32_bf16(ql[rg][1], kh1, u, 0, 0, 0);
                    u = __builtin_amdgcn_mfma_f32_16x16x32_bf16(qh[rg][0], kl0, u, 0, 0, 0);
                    u = __builtin_amdgcn_mfma_f32_16x16x32_bf16(qh[rg][1], kl1, u, 0, 0, 0);
#pragma unroll
                    for (int r = 0; r < 4; ++r)
                        P[wv][rg * 16 + lg * 4 + r][cg * 16 + lr] =
                            (__bf16)(__expf(u[r]) * rz[rg][r]);
                }
            }
            // PV from staged V + P strip
            {
                bf16x8 vb[4][2];
#pragma unroll
                for (int dg = 0; dg < 4; ++dg)
#pragma unroll
                    for (int kk = 0; kk < 2; ++kk)
                        vb[dg][kk] = *(const bf16x8*)&VTS[cur][dg * 16 + lr][kk * 32 + lg * 8];
#pragma unroll
                for (int rg = 0; rg < 2; ++rg) {
                    const bf16x8 pa0 = *(const bf16x8*)&P[wv][rg * 16 + lr][lg * 8];
                    const bf16x8 pa1 = *(const bf16x8*)&P[wv][rg * 16 + lr][32 + lg * 8];
#pragma unroll
                    for (int dg = 0; dg < 4; ++dg) {
                        pv[rg][dg] = __builtin_amdgcn_mfma_f32_16x16x32_bf16(pa0, vb[dg][0], pv[rg][dg], 0, 0, 0);
                        pv[rg][dg] = __builtin_amdgcn_mfma_f32_16x16x32_bf16(pa1, vb[dg][1], pv[rg][dg], 0, 0, 0);
                    }
                }
            }
            // weights: float4 nt stores from the P strip (round-9 path)
#pragma unroll
            for (int it = 0; it < 8; ++it) {
                const int row = it * 4 + lg;
                const bf16x4 u = *(const bf16x4*)&P[wv][row][lr * 4];
                f32x4 o;
                o[0] = (float)u[0]; o[1] = (float)u[1];
                o[2] = (float)u[2]; o[3] = (float)u[3];
                __builtin_nontemporal_store(o, (f32x4*)(wbase + (size_t)row * SS + j0 + lr * 4));
            }
            // stage next tile (regs -> LDS), then lgkmcnt-only barrier
            if (jt + 1 < 32) {
                *(bf16x8*)&KH[cur ^ 1][srow][scol] = sh;
                *(bf16x8*)&KL[cur ^ 1][srow][scol] = sl;
                *(bf16x8*)&VTS[cur ^ 1][srow][scol] = sv;
            }
            lds_barrier();
        }
    }

    {   // av -> bf16 ws [B][S][E]
        const int b = bh >> 4, h = bh & 15;
#pragma unroll
        for (int rg = 0; rg < 2; ++rg)
#pragma unroll
            for (int dg = 0; dg < 4; ++dg)
#pragma unroll
                for (int r = 0; r < 4; ++r) {
                    const int s = q0 + rg * 16 + lg * 4 + r;
                    av_ws[((size_t)(b * SS + s)) * EE + h * HD + dg * 16 + lr] =
                        (__bf16)pv[rg][dg][r];
                }
    }
}

// ---------------- K3: out projection (plain bf16) -------------------------
__global__ __launch_bounds__(256) void k_oproj(
    const __bf16* __restrict__ av_ws, const float* __restrict__ w_out,
    const float* __restrict__ b_out, float* __restrict__ out)
{
    __shared__ __bf16 Abf[128][72];
    __shared__ __bf16 Bbf[64][72];
    const int tid = threadIdx.x;
    const int lane = tid & 63;
    const int wv = tid >> 6;
    const int m0 = blockIdx.y * 128, f0 = blockIdx.x * 64;
    const int wr = (wv >> 1) * 64, wc = (wv & 1) * 32;
    const int lr = lane & 15, lg = lane >> 4;

    f32x4 acc[4][2];
#pragma unroll
    for (int a = 0; a < 4; ++a)
#pragma unroll
        for (int b = 0; b < 2; ++b) acc[a][b] = (f32x4){0.f, 0.f, 0.f, 0.f};

    for (int kt = 0; kt < 16; ++kt) {
        const int k0 = kt * 64;
        __syncthreads();
        {
            const int c = tid & 7, r0 = tid >> 3;
#pragma unroll
            for (int i = 0; i < 4; ++i) {
                const int row = r0 + i * 32;
                *(bf16x8*)&Abf[row][c * 8] =
                    *(const bf16x8*)(av_ws + (size_t)(m0 + row) * EE + k0 + c * 8);
            }
        }
        {
            const int c = tid & 15, r0 = tid >> 4;
#pragma unroll
            for (int i = 0; i < 4; ++i) {
                const int row = r0 + i * 16;
                const float4 v = *(const float4*)(w_out + (size_t)(f0 + row) * EE + k0 + c * 4);
                bf16x4 pk;
                pk[0] = (__bf16)v.x; pk[1] = (__bf16)v.y;
                pk[2] = (__bf16)v.z; pk[3] = (__bf16)v.w;
                *(bf16x4*)&Bbf[row][c * 4] = pk;
            }
        }
        __syncthreads();
#pragma unroll
        for (int ks = 0; ks < 2; ++ks) {
            const int koff = ks * 32 + lg * 8;
            bf16x8 a[4], b[2];
#pragma unroll
            for (int rt = 0; rt < 4; ++rt) a[rt] = *(const bf16x8*)&Abf[wr + rt * 16 + lr][koff];
#pragma unroll
            for (int ct = 0; ct < 2; ++ct) b[ct] = *(const bf16x8*)&Bbf[wc + ct * 16 + lr][koff];
#pragma unroll
            for (int rt = 0; rt < 4; ++rt)
#pragma unroll
                for (int ct = 0; ct < 2; ++ct)
                    acc[rt][ct] = __builtin_amdgcn_mfma_f32_16x16x32_bf16(a[rt], b[ct], acc[rt][ct], 0, 0, 0);
        }
    }
#pragma unroll
    for (int rt = 0; rt < 4; ++rt) {
        const int m = m0 + wr + rt * 16 + lg * 4;
#pragma unroll
        for (int ct = 0; ct < 2; ++ct) {
            const int f = f0 + wc + ct * 16 + lr;
            const float bo = b_out[f];
#pragma unroll
            for (int r = 0; r < 4; ++r)
                __builtin_nontemporal_store(acc[rt][ct][r] + bo,
                                            out + (size_t)(m + r) * EE + f);
        }
    }
}

extern "C" void kernel_launch(void* const* d_in, const int* in_sizes, int n_in,
                              void* d_out, int out_size, void* d_ws, size_t ws_size,
                              hipStream_t stream)
{
    const float* x    = (const float*)d_in[0];
    const float* wqkv = (const float*)d_in[1];
    const float* bqkv = (const float*)d_in[2];
    const float* wo   = (const float*)d_in[3];
    const float* bo   = (const float*)d_in[4];
    const float* rel  = (const float*)d_in[5];

    float* out = (float*)d_out;
    float* wts = out + (size_t)BB * SS * EE;      // weights region, written by K2

    const size_t NQ = (size_t)BB * HH * SS * HD;  // 4M elements
    __bf16* qhi_ws = (__bf16*)d_ws;               // 8 MB each
    __bf16* qlo_ws = qhi_ws + NQ;
    __bf16* khi_ws = qlo_ws + NQ;
    __bf16* klo_ws = khi_ws + NQ;
    __bf16* vt_ws  = klo_ws + NQ;
    __bf16* av_ws  = vt_ws + NQ;                  // ws total: 48 MB

    k_qkv<<<dim3(48, 32), 256, 0, stream>>>(x, wqkv, bqkv, rel,
                                            qhi_ws, qlo_ws, khi_ws, klo_ws, vt_ws);
    k_attn10<<<dim3(256), 512, 0, stream>>>(qhi_ws, qlo_ws, khi_ws, klo_ws,
                                            vt_ws, wts, av_ws);
    k_oproj<<<dim3(EE / 64, (BB * SS) / 128), 256, 0, stream>>>(av_ws, wo, bo, out);
}

// Round 12
// 292.753 us; speedup vs baseline: 1.2279x; 1.0154x over previous
//
#include <hip/hip_runtime.h>
#include <hip/hip_bf16.h>

#define BB 2
#define SS 2048
#define EE 1024
#define HH 16
#define HD 64

typedef __attribute__((ext_vector_type(8))) __bf16 bf16x8;
typedef __attribute__((ext_vector_type(4))) __bf16 bf16x4;
typedef __attribute__((ext_vector_type(2))) __bf16 bf16x2;
typedef __attribute__((ext_vector_type(4))) float f32x4;
typedef __attribute__((ext_vector_type(2))) float f32x2;

__device__ __forceinline__ void split2(float x, __bf16& h, __bf16& l) {
    h = (__bf16)x;                 // RTNE
    l = (__bf16)(x - (float)h);    // residual
}

// lgkmcnt-only barrier: orders LDS ops block-wide without draining
// outstanding global (nt) stores.
__device__ __forceinline__ void lds_barrier() {
    asm volatile("s_waitcnt lgkmcnt(0)" ::: "memory");
    __builtin_amdgcn_s_barrier();
    __builtin_amdgcn_sched_barrier(0);
}

// ---------------- K1: QKV projection, fused fp32->hi/lo split staging -----
__global__ __launch_bounds__(256) void k_qkv(
    const float* __restrict__ xx, const float* __restrict__ ww,
    const float* __restrict__ bqkv, const float* __restrict__ rel,
    __bf16* __restrict__ qhi_ws, __bf16* __restrict__ qlo_ws,
    __bf16* __restrict__ khi_ws, __bf16* __restrict__ klo_ws,
    __bf16* __restrict__ vt_ws)
{
    __shared__ __bf16 Ahi[128][72], Alo[128][72];
    __shared__ __bf16 Bhi[64][72],  Blo[64][72];

    const int tid = threadIdx.x;
    const int lane = tid & 63;
    const int wv = tid >> 6;
    const int m0 = blockIdx.y * 128;
    const int f0 = blockIdx.x * 64;
    const int wr = (wv >> 1) * 64, wc = (wv & 1) * 32;
    const int lr = lane & 15, lg = lane >> 4;

    f32x4 acc[4][2];
#pragma unroll
    for (int a = 0; a < 4; ++a)
#pragma unroll
        for (int b = 0; b < 2; ++b) acc[a][b] = (f32x4){0.f, 0.f, 0.f, 0.f};

    for (int kt = 0; kt < 16; ++kt) {
        const int k0 = kt * 64;
        __syncthreads();
        {   // stage A tile 128x64: fp32 load -> split -> hi/lo LDS
            const int c = tid & 7, r0 = tid >> 3;
#pragma unroll
            for (int i = 0; i < 4; ++i) {
                const int row = r0 + i * 32;
                const float* gp = xx + (size_t)(m0 + row) * EE + k0 + c * 8;
                const float4 v0 = *(const float4*)gp;
                const float4 v1 = *(const float4*)(gp + 4);
                float t[8] = {v0.x, v0.y, v0.z, v0.w, v1.x, v1.y, v1.z, v1.w};
                bf16x8 hi, lo;
#pragma unroll
                for (int e = 0; e < 8; ++e) {
                    __bf16 h, l; split2(t[e], h, l);
                    hi[e] = h; lo[e] = l;
                }
                *(bf16x8*)&Ahi[row][c * 8] = hi;
                *(bf16x8*)&Alo[row][c * 8] = lo;
            }
        }
        {   // stage B tile 64x64: fp32 load -> split -> hi/lo LDS
            const int c = tid & 7, r0 = tid >> 3;
#pragma unroll
            for (int i = 0; i < 2; ++i) {
                const int row = r0 + i * 32;
                const float* gp = ww + (size_t)(f0 + row) * EE + k0 + c * 8;
                const float4 v0 = *(const float4*)gp;
                const float4 v1 = *(const float4*)(gp + 4);
                float t[8] = {v0.x, v0.y, v0.z, v0.w, v1.x, v1.y, v1.z, v1.w};
                bf16x8 hi, lo;
#pragma unroll
                for (int e = 0; e < 8; ++e) {
                    __bf16 h, l; split2(t[e], h, l);
                    hi[e] = h; lo[e] = l;
                }
                *(bf16x8*)&Bhi[row][c * 8] = hi;
                *(bf16x8*)&Blo[row][c * 8] = lo;
            }
        }
        __syncthreads();
#pragma unroll
        for (int ks = 0; ks < 2; ++ks) {
            const int koff = ks * 32 + lg * 8;
            bf16x8 ah[4], al[4], bh[2], bl[2];
#pragma unroll
            for (int rt = 0; rt < 4; ++rt) {
                ah[rt] = *(const bf16x8*)&Ahi[wr + rt * 16 + lr][koff];
                al[rt] = *(const bf16x8*)&Alo[wr + rt * 16 + lr][koff];
            }
#pragma unroll
            for (int ct = 0; ct < 2; ++ct) {
                bh[ct] = *(const bf16x8*)&Bhi[wc + ct * 16 + lr][koff];
                bl[ct] = *(const bf16x8*)&Blo[wc + ct * 16 + lr][koff];
            }
#pragma unroll
            for (int rt = 0; rt < 4; ++rt)
#pragma unroll
                for (int ct = 0; ct < 2; ++ct) {
                    acc[rt][ct] = __builtin_amdgcn_mfma_f32_16x16x32_bf16(ah[rt], bh[ct], acc[rt][ct], 0, 0, 0);
                    acc[rt][ct] = __builtin_amdgcn_mfma_f32_16x16x32_bf16(al[rt], bh[ct], acc[rt][ct], 0, 0, 0);
                    acc[rt][ct] = __builtin_amdgcn_mfma_f32_16x16x32_bf16(ah[rt], bl[ct], acc[rt][ct], 0, 0, 0);
                }
        }
    }

    const int blk = f0 >> 6;             // 0..47
    const int h = blk / 3, typ = blk % 3;
#pragma unroll
    for (int rt = 0; rt < 4; ++rt) {
        const int m = m0 + wr + rt * 16 + lg * 4;
        const int b = m >> 11, s = m & 2047;
#pragma unroll
        for (int ct = 0; ct < 2; ++ct) {
            const int d = wc + ct * 16 + lr;
            const float bq = bqkv[f0 + d];
            if (typ == 0) {
                const size_t base = ((size_t)(b * HH + h) * SS + s) * HD + d;
#pragma unroll
                for (int r = 0; r < 4; ++r) {
                    __bf16 hh, ll; split2(acc[rt][ct][r] + bq, hh, ll);
                    qhi_ws[base + (size_t)r * HD] = hh;
                    qlo_ws[base + (size_t)r * HD] = ll;
                }
            } else if (typ == 1) {
                const size_t base = ((size_t)(b * HH + h) * SS + s) * HD + d;
                const size_t rb = ((size_t)h * SS + s) * HD + d;
#pragma unroll
                for (int r = 0; r < 4; ++r) {
                    const float t = (acc[rt][ct][r] + bq) * 0.125f + rel[rb + (size_t)r * HD];
                    __bf16 hh, ll; split2(t, hh, ll);
                    khi_ws[base + (size_t)r * HD] = hh;
                    klo_ws[base + (size_t)r * HD] = ll;
                }
            } else {
                const size_t base = ((size_t)(b * HH + h) * HD + d) * SS + s;
                bf16x4 pk;
#pragma unroll
                for (int r = 0; r < 4; ++r) pk[r] = (__bf16)(acc[rt][ct][r] + bq);
                *(bf16x4*)&vt_ws[base] = pk;
            }
        }
    }
}

// ---------------- K2: two-pass attention, 512B-contiguous store bursts ----
// Round-11 structure with ONE change: pass 2 buffers TWO j-tiles of
// normalized P per wave (P4 strip), then writes weights as 512B-contiguous
// full-wave nt stores (f32x2 per lane) -- 2x segment size, rows in full
// runs -- instead of 4x256B scattered segments per instruction.
__global__ __launch_bounds__(512, 1) void k_attn11(
    const __bf16* __restrict__ qhi_ws, const __bf16* __restrict__ qlo_ws,
    const __bf16* __restrict__ khi_ws, const __bf16* __restrict__ klo_ws,
    const __bf16* __restrict__ vt_ws,
    float* __restrict__ wts, __bf16* __restrict__ av_ws)
{
    __shared__ __bf16 KH[2][64][72], KL[2][64][72], VTS[2][64][72]; // 55.3 KB
    __shared__ __bf16 P4[8][32][130];                               // 66.6 KB

    const int tid = threadIdx.x;
    const int lane = tid & 63;
    const int wv = tid >> 6;          // 0..7
    const int lr = lane & 15, lg = lane >> 4;

    // XCD swizzle: 256 blocks; XCD k gets wgid k*32..k*32+31 = 4 whole bh
    const int wgid = (blockIdx.x & 7) * 32 + (blockIdx.x >> 3);
    const int bh = wgid >> 3;
    const int q0 = (wgid & 7) * 256 + wv * 32;
    const size_t kvb = (size_t)bh * SS * HD;

    const int srow = tid >> 3;          // 0..63
    const int scol = (tid & 7) * 8;     // 0..56

    // q fragments (hi/lo), 2 row-groups x 2 k-chunks
    bf16x8 qh[2][2], ql[2][2];
#pragma unroll
    for (int rg = 0; rg < 2; ++rg) {
        const size_t ro = kvb + (size_t)(q0 + rg * 16 + lr) * HD + lg * 8;
#pragma unroll
        for (int kk = 0; kk < 2; ++kk) {
            qh[rg][kk] = *(const bf16x8*)(qhi_ws + ro + kk * 32);
            ql[rg][kk] = *(const bf16x8*)(qlo_ws + ro + kk * 32);
        }
    }

    const __bf16* khp = khi_ws + kvb;
    const __bf16* klp = klo_ws + kvb;
    const __bf16* vtp = vt_ws + kvb;

    // ---- pass 1: Z ----
    float z[2][4] = {{0.f,0.f,0.f,0.f},{0.f,0.f,0.f,0.f}};
    {
        bf16x8 sh = *(const bf16x8*)(khp + (size_t)srow * HD + scol);
        bf16x8 sl = *(const bf16x8*)(klp + (size_t)srow * HD + scol);
        *(bf16x8*)&KH[0][srow][scol] = sh;
        *(bf16x8*)&KL[0][srow][scol] = sl;
        lds_barrier();
        for (int jt = 0; jt < 32; ++jt) {
            const int cur = jt & 1;
            if (jt + 1 < 32) {               // prefetch next tile into regs
                const size_t ro = ((size_t)(jt + 1) * 64 + srow) * HD + scol;
                sh = *(const bf16x8*)(khp + ro);
                sl = *(const bf16x8*)(klp + ro);
            }
#pragma unroll
            for (int cg = 0; cg < 4; ++cg) {
                const bf16x8 kh0 = *(const bf16x8*)&KH[cur][cg * 16 + lr][lg * 8];
                const bf16x8 kh1 = *(const bf16x8*)&KH[cur][cg * 16 + lr][32 + lg * 8];
                const bf16x8 kl0 = *(const bf16x8*)&KL[cur][cg * 16 + lr][lg * 8];
                const bf16x8 kl1 = *(const bf16x8*)&KL[cur][cg * 16 + lr][32 + lg * 8];
#pragma unroll
                for (int rg = 0; rg < 2; ++rg) {
                    f32x4 u = (f32x4){0.f, 0.f, 0.f, 0.f};
                    u = __builtin_amdgcn_mfma_f32_16x16x32_bf16(qh[rg][0], kh0, u, 0, 0, 0);
                    u = __builtin_amdgcn_mfma_f32_16x16x32_bf16(qh[rg][1], kh1, u, 0, 0, 0);
                    u = __builtin_amdgcn_mfma_f32_16x16x32_bf16(ql[rg][0], kh0, u, 0, 0, 0);
                    u = __builtin_amdgcn_mfma_f32_16x16x32_bf16(ql[rg][1], kh1, u, 0, 0, 0);
                    u = __builtin_amdgcn_mfma_f32_16x16x32_bf16(qh[rg][0], kl0, u, 0, 0, 0);
                    u = __builtin_amdgcn_mfma_f32_16x16x32_bf16(qh[rg][1], kl1, u, 0, 0, 0);
#pragma unroll
                    for (int r = 0; r < 4; ++r) z[rg][r] += __expf(u[r]);
                }
            }
            if (jt + 1 < 32) {               // stage next tile (regs -> LDS)
                *(bf16x8*)&KH[cur ^ 1][srow][scol] = sh;
                *(bf16x8*)&KL[cur ^ 1][srow][scol] = sl;
            }
            lds_barrier();
        }
    }
    // butterfly over the 16 lr lanes -> every lane holds Z for its rows
#pragma unroll
    for (int m = 1; m < 16; m <<= 1)
#pragma unroll
        for (int rg = 0; rg < 2; ++rg)
#pragma unroll
            for (int r = 0; r < 4; ++r) z[rg][r] += __shfl_xor(z[rg][r], m, 64);
    float rz[2][4];
#pragma unroll
    for (int rg = 0; rg < 2; ++rg)
#pragma unroll
        for (int r = 0; r < 4; ++r) rz[rg][r] = 1.0f / z[rg][r];

    // ---- pass 2: weights + PV ----
    f32x4 pv[2][4];
#pragma unroll
    for (int rg = 0; rg < 2; ++rg)
#pragma unroll
        for (int dg = 0; dg < 4; ++dg) pv[rg][dg] = (f32x4){0.f, 0.f, 0.f, 0.f};

    float* wbase = wts + ((size_t)bh * SS + q0) * SS;

    {
        bf16x8 sh = *(const bf16x8*)(khp + (size_t)srow * HD + scol);
        bf16x8 sl = *(const bf16x8*)(klp + (size_t)srow * HD + scol);
        bf16x8 sv = *(const bf16x8*)(vtp + (size_t)srow * SS + scol);
        *(bf16x8*)&KH[0][srow][scol] = sh;
        *(bf16x8*)&KL[0][srow][scol] = sl;
        *(bf16x8*)&VTS[0][srow][scol] = sv;
        lds_barrier();
        for (int jp = 0; jp < 16; ++jp) {
#pragma unroll
            for (int t = 0; t < 2; ++t) {
                const int jt = jp * 2 + t;
                const int cur = jt & 1;
                const int j0 = jt * 64;
                if (jt + 1 < 32) {
                    const size_t ro = ((size_t)(jt + 1) * 64 + srow) * HD + scol;
                    sh = *(const bf16x8*)(khp + ro);
                    sl = *(const bf16x8*)(klp + ro);
                    sv = *(const bf16x8*)(vtp + (size_t)srow * SS + j0 + 64 + scol);
                }
                // QK + exp -> normalized P (bf16) into the 2-jt P4 strip
#pragma unroll
                for (int cg = 0; cg < 4; ++cg) {
                    const bf16x8 kh0 = *(const bf16x8*)&KH[cur][cg * 16 + lr][lg * 8];
                    const bf16x8 kh1 = *(const bf16x8*)&KH[cur][cg * 16 + lr][32 + lg * 8];
                    const bf16x8 kl0 = *(const bf16x8*)&KL[cur][cg * 16 + lr][lg * 8];
                    const bf16x8 kl1 = *(const bf16x8*)&KL[cur][cg * 16 + lr][32 + lg * 8];
#pragma unroll
                    for (int rg = 0; rg < 2; ++rg) {
                        f32x4 u = (f32x4){0.f, 0.f, 0.f, 0.f};
                        u = __builtin_amdgcn_mfma_f32_16x16x32_bf16(qh[rg][0], kh0, u, 0, 0, 0);
                        u = __builtin_amdgcn_mfma_f32_16x16x32_bf16(qh[rg][1], kh1, u, 0, 0, 0);
                        u = __builtin_amdgcn_mfma_f32_16x16x32_bf16(ql[rg][0], kh0, u, 0, 0, 0);
                        u = __builtin_amdgcn_mfma_f32_16x16x32_bf16(ql[rg][1], kh1, u, 0, 0, 0);
                        u = __builtin_amdgcn_mfma_f32_16x16x32_bf16(qh[rg][0], kl0, u, 0, 0, 0);
                        u = __builtin_amdgcn_mfma_f32_16x16x32_bf16(qh[rg][1], kl1, u, 0, 0, 0);
#pragma unroll
                        for (int r = 0; r < 4; ++r)
                            P4[wv][rg * 16 + lg * 4 + r][t * 64 + cg * 16 + lr] =
                                (__bf16)(__expf(u[r]) * rz[rg][r]);
                    }
                }
                // PV from staged V + P4 strip
                {
                    bf16x8 vb[4][2];
#pragma unroll
                    for (int dg = 0; dg < 4; ++dg)
#pragma unroll
                        for (int kk = 0; kk < 2; ++kk)
                            vb[dg][kk] = *(const bf16x8*)&VTS[cur][dg * 16 + lr][kk * 32 + lg * 8];
#pragma unroll
                    for (int rg = 0; rg < 2; ++rg) {
                        const bf16x8 pa0 = *(const bf16x8*)&P4[wv][rg * 16 + lr][t * 64 + lg * 8];
                        const bf16x8 pa1 = *(const bf16x8*)&P4[wv][rg * 16 + lr][t * 64 + 32 + lg * 8];
#pragma unroll
                        for (int dg = 0; dg < 4; ++dg) {
                            pv[rg][dg] = __builtin_amdgcn_mfma_f32_16x16x32_bf16(pa0, vb[dg][0], pv[rg][dg], 0, 0, 0);
                            pv[rg][dg] = __builtin_amdgcn_mfma_f32_16x16x32_bf16(pa1, vb[dg][1], pv[rg][dg], 0, 0, 0);
                        }
                    }
                }
                // stage next tile (regs -> LDS)
                if (jt + 1 < 32) {
                    *(bf16x8*)&KH[cur ^ 1][srow][scol] = sh;
                    *(bf16x8*)&KL[cur ^ 1][srow][scol] = sl;
                    *(bf16x8*)&VTS[cur ^ 1][srow][scol] = sv;
                }
                if (t == 1) {
                    // burst: 32 rows x 512B-contiguous full-wave nt stores
                    const int jc = jp * 128;
#pragma unroll 8
                    for (int it = 0; it < 32; ++it) {
                        const bf16x2 u = *(const bf16x2*)&P4[wv][it][lane * 2];
                        f32x2 o;
                        o[0] = (float)u[0]; o[1] = (float)u[1];
                        __builtin_nontemporal_store(
                            o, (f32x2*)(wbase + (size_t)it * SS + jc + lane * 2));
                    }
                }
                lds_barrier();
            }
        }
    }

    {   // av -> bf16 ws [B][S][E]
        const int b = bh >> 4, h = bh & 15;
#pragma unroll
        for (int rg = 0; rg < 2; ++rg)
#pragma unroll
            for (int dg = 0; dg < 4; ++dg)
#pragma unroll
                for (int r = 0; r < 4; ++r) {
                    const int s = q0 + rg * 16 + lg * 4 + r;
                    av_ws[((size_t)(b * SS + s)) * EE + h * HD + dg * 16 + lr] =
                        (__bf16)pv[rg][dg][r];
                }
    }
}

// ---------------- K3: out projection (plain bf16) -------------------------
__global__ __launch_bounds__(256) void k_oproj(
    const __bf16* __restrict__ av_ws, const float* __restrict__ w_out,
    const float* __restrict__ b_out, float* __restrict__ out)
{
    __shared__ __bf16 Abf[128][72];
    __shared__ __bf16 Bbf[64][72];
    const int tid = threadIdx.x;
    const int lane = tid & 63;
    const int wv = tid >> 6;
    const int m0 = blockIdx.y * 128, f0 = blockIdx.x * 64;
    const int wr = (wv >> 1) * 64, wc = (wv & 1) * 32;
    const int lr = lane & 15, lg = lane >> 4;

    f32x4 acc[4][2];
#pragma unroll
    for (int a = 0; a < 4; ++a)
#pragma unroll
        for (int b = 0; b < 2; ++b) acc[a][b] = (f32x4){0.f, 0.f, 0.f, 0.f};

    for (int kt = 0; kt < 16; ++kt) {
        const int k0 = kt * 64;
        __syncthreads();
        {
            const int c = tid & 7, r0 = tid >> 3;
#pragma unroll
            for (int i = 0; i < 4; ++i) {
                const int row = r0 + i * 32;
                *(bf16x8*)&Abf[row][c * 8] =
                    *(const bf16x8*)(av_ws + (size_t)(m0 + row) * EE + k0 + c * 8);
            }
        }
        {
            const int c = tid & 15, r0 = tid >> 4;
#pragma unroll
            for (int i = 0; i < 4; ++i) {
                const int row = r0 + i * 16;
                const float4 v = *(const float4*)(w_out + (size_t)(f0 + row) * EE + k0 + c * 4);
                bf16x4 pk;
                pk[0] = (__bf16)v.x; pk[1] = (__bf16)v.y;
                pk[2] = (__bf16)v.z; pk[3] = (__bf16)v.w;
                *(bf16x4*)&Bbf[row][c * 4] = pk;
            }
        }
        __syncthreads();
#pragma unroll
        for (int ks = 0; ks < 2; ++ks) {
            const int koff = ks * 32 + lg * 8;
            bf16x8 a[4], b[2];
#pragma unroll
            for (int rt = 0; rt < 4; ++rt) a[rt] = *(const bf16x8*)&Abf[wr + rt * 16 + lr][koff];
#pragma unroll
            for (int ct = 0; ct < 2; ++ct) b[ct] = *(const bf16x8*)&Bbf[wc + ct * 16 + lr][koff];
#pragma unroll
            for (int rt = 0; rt < 4; ++rt)
#pragma unroll
                for (int ct = 0; ct < 2; ++ct)
                    acc[rt][ct] = __builtin_amdgcn_mfma_f32_16x16x32_bf16(a[rt], b[ct], acc[rt][ct], 0, 0, 0);
        }
    }
#pragma unroll
    for (int rt = 0; rt < 4; ++rt) {
        const int m = m0 + wr + rt * 16 + lg * 4;
#pragma unroll
        for (int ct = 0; ct < 2; ++ct) {
            const int f = f0 + wc + ct * 16 + lr;
            const float bo = b_out[f];
#pragma unroll
            for (int r = 0; r < 4; ++r)
                __builtin_nontemporal_store(acc[rt][ct][r] + bo,
                                            out + (size_t)(m + r) * EE + f);
        }
    }
}

extern "C" void kernel_launch(void* const* d_in, const int* in_sizes, int n_in,
                              void* d_out, int out_size, void* d_ws, size_t ws_size,
                              hipStream_t stream)
{
    const float* x    = (const float*)d_in[0];
    const float* wqkv = (const float*)d_in[1];
    const float* bqkv = (const float*)d_in[2];
    const float* wo   = (const float*)d_in[3];
    const float* bo   = (const float*)d_in[4];
    const float* rel  = (const float*)d_in[5];

    float* out = (float*)d_out;
    float* wts = out + (size_t)BB * SS * EE;      // weights region, written by K2

    const size_t NQ = (size_t)BB * HH * SS * HD;  // 4M elements
    __bf16* qhi_ws = (__bf16*)d_ws;               // 8 MB each
    __bf16* qlo_ws = qhi_ws + NQ;
    __bf16* khi_ws = qlo_ws + NQ;
    __bf16* klo_ws = khi_ws + NQ;
    __bf16* vt_ws  = klo_ws + NQ;
    __bf16* av_ws  = vt_ws + NQ;                  // ws total: 48 MB

    k_qkv<<<dim3(48, 32), 256, 0, stream>>>(x, wqkv, bqkv, rel,
                                            qhi_ws, qlo_ws, khi_ws, klo_ws, vt_ws);
    k_attn11<<<dim3(256), 512, 0, stream>>>(qhi_ws, qlo_ws, khi_ws, klo_ws,
                                            vt_ws, wts, av_ws);
    k_oproj<<<dim3(EE / 64, (BB * SS) / 128), 256, 0, stream>>>(av_ws, wo, bo, out);
}